// Round 1
// baseline (2349.681 us; speedup 1.0000x reference)
//
#include <hip/hip_runtime.h>

// LocalFeatureAggregation — f32 baseline, fused per-stage pipeline.
// B=2, N=16384, K=16, D_IN=128, D_OUT=256, GROUPS=16.
//
// Pipeline (all on `stream`):
//  0. zero stats (5 sets x 64 floats)
//  1. sc conv  (features->S, 512ch) + GN stats          [conv MODE 2]
//  2. mlp1     (features->X1, 128ch, leaky 0.2)         [conv MODE 1]
//  3. lse1 stats  (recompute geo conv, reduce sum/sq)
//  4. lse1 m      (geo GN+relu+meanK || gather-meanK)   -> M (256ch)
//  5. pool1 conv  (M->Z 128ch) + GN stats               [conv MODE 2]
//  6. GN+relu in place on Z (x2)
//  7. lse2 stats
//  8. lse2 m   (xprev = Z)                              -> M
//  9. pool2 conv  (M->Z 256ch) + GN stats
// 10. GN+relu in place on Z (x3)
// 11. final: mlp2(Z) + GN(S) -> leaky 0.01 -> d_out     [conv MODE 3]
//
// ws usage: S 64MB | X1 16MB | M 32MB | Z 32MB | stats 2KB  => ~151MB

constexpr int Bc = 2;
constexpr int Nc = 16384;
constexpr int Kc = 16;
constexpr float EPSc = 1e-6f;

// ---- workspace layout (in floats) ----
constexpr size_t SZ_S  = (size_t)Bc * 512 * Nc;   // 16,777,216
constexpr size_t SZ_X1 = (size_t)Bc * 128 * Nc;   //  4,194,304
constexpr size_t SZ_M  = (size_t)Bc * 256 * Nc;   //  8,388,608
constexpr size_t SZ_Z  = (size_t)Bc * 256 * Nc;   //  8,388,608
constexpr size_t OFF_S  = 0;
constexpr size_t OFF_X1 = OFF_S + SZ_S;
constexpr size_t OFF_M  = OFF_X1 + SZ_X1;
constexpr size_t OFF_Z  = OFF_M + SZ_M;
constexpr size_t OFF_ST = OFF_Z + SZ_Z;

__global__ void zero_kernel(float* __restrict__ p, int n) {
    int i = blockIdx.x * 256 + threadIdx.x;
    if (i < n) p[i] = 0.f;
}

// Generic 1x1 conv over channel-planar [b][C][N] tensors.
// MODE 0: plain   MODE 1: leaky 0.2   MODE 2: raw out + group stats (atomics)
// MODE 3: final — out = leaky0.01( conv + GN(sbuf; st_sc, gw, gb) )
template<int CIN, int COUT, int GROUP_CH, int MODE, int TN>
__launch_bounds__(256)
__global__ void conv_kernel(const float* __restrict__ in,
                            const float* __restrict__ w,
                            const float* __restrict__ bias,
                            float* __restrict__ out,
                            float* __restrict__ stats,
                            const float* __restrict__ sbuf,
                            const float* __restrict__ st_sc,
                            const float* __restrict__ gw,
                            const float* __restrict__ gb,
                            float sc_cnt)
{
    constexpr int OG  = 256 / TN;     // output thread-groups
    constexpr int OPT = COUT / OG;    // outputs per thread
    constexpr int LG  = 16 / OG;      // groups spanned per thread (MODE 2)
    __shared__ float tile[CIN * TN];
    __shared__ float sstat[32];
    __shared__ float smean[16], sinv[16];

    const int nt  = Nc / TN;
    const int b   = blockIdx.x / nt;
    const int n0  = (blockIdx.x % nt) * TN;
    const int tid = threadIdx.x;

    const float* inb = in + ((size_t)b * CIN) * Nc + n0;
    #pragma unroll 4
    for (int e = tid; e < CIN * TN; e += 256) {
        int c = e / TN, i = e % TN;
        tile[e] = inb[(size_t)c * Nc + i];
    }
    if constexpr (MODE == 2) { if (tid < 32) sstat[tid] = 0.f; }
    if constexpr (MODE == 3) {
        if (tid < 16) {
            float s0 = st_sc[(b * 16 + tid) * 2 + 0];
            float s1 = st_sc[(b * 16 + tid) * 2 + 1];
            float mean = s0 / sc_cnt;
            float var  = s1 / sc_cnt - mean * mean;
            smean[tid] = mean;
            sinv[tid]  = rsqrtf(var + EPSc);
        }
    }
    __syncthreads();

    const int tn = tid % TN;
    const int og = tid / TN;
    float gsum[LG], gsq[LG];
    #pragma unroll
    for (int i = 0; i < LG; i++) { gsum[i] = 0.f; gsq[i] = 0.f; }

    for (int ch = 0; ch < OPT; ch += 8) {
        const int o0 = og * OPT + ch;
        float acc[8];
        #pragma unroll
        for (int j = 0; j < 8; j++) acc[j] = bias[o0 + j];
        #pragma unroll 4
        for (int c = 0; c < CIN; c++) {
            float r = tile[c * TN + tn];
            #pragma unroll
            for (int j = 0; j < 8; j++)
                acc[j] += w[(size_t)(o0 + j) * CIN + c] * r;
        }
        #pragma unroll
        for (int j = 0; j < 8; j++) {
            int o = o0 + j;
            float v = acc[j];
            if constexpr (MODE == 1) v = v > 0.f ? v : 0.2f * v;
            if constexpr (MODE == 2) {
                int lg = (o / GROUP_CH) % LG;
                gsum[lg] += v; gsq[lg] += v * v;
            }
            if constexpr (MODE == 3) {
                int g = o / GROUP_CH;
                float s  = sbuf[((size_t)b * COUT + o) * Nc + n0 + tn];
                float sn = (s - smean[g]) * sinv[g] * gw[o] + gb[o];
                v += sn;
                v = v > 0.f ? v : 0.01f * v;
            }
            out[((size_t)b * COUT + o) * Nc + n0 + tn] = v;
        }
    }
    if constexpr (MODE == 2) {
        #pragma unroll
        for (int lg = 0; lg < LG; lg++) {
            int g = og * LG + lg;
            atomicAdd(&sstat[g * 2 + 0], gsum[lg]);
            atomicAdd(&sstat[g * 2 + 1], gsq[lg]);
        }
        __syncthreads();
        if (tid < 32) atomicAdd(&stats[b * 32 + tid], sstat[tid]);
    }
}

// LSE geo-conv stats: one thread per (b,n,k); recompute y[o] for all 128 o,
// reduce sum/sumsq per group (8 ch/group) via LDS + global atomics.
__launch_bounds__(256)
__global__ void lse_stats_kernel(const float* __restrict__ coords,
                                 const int* __restrict__ knn_idx,
                                 const float* __restrict__ knn_dist,
                                 const float* __restrict__ w,     // [128][10]
                                 const float* __restrict__ bias,  // [128]
                                 float* __restrict__ stats)       // [B][16][2]
{
    __shared__ float wl[1280];
    __shared__ float bl[128];
    __shared__ float sstat[32];
    int tid = threadIdx.x;
    for (int e = tid; e < 1280; e += 256) wl[e] = w[e];
    if (tid < 128) bl[tid] = bias[tid];
    if (tid < 32)  sstat[tid] = 0.f;
    __syncthreads();

    int gt = blockIdx.x * 256 + tid;         // < B*N*K = 524288
    int b  = gt / (Nc * Kc);
    int r  = gt % (Nc * Kc);
    int n  = r / Kc;
    const float* cb = coords + (size_t)b * Nc * 3;
    float cx = cb[n*3+0], cy = cb[n*3+1], cz = cb[n*3+2];
    int   j  = knn_idx[(size_t)b * Nc * Kc + r];
    float nx = cb[j*3+0], ny = cb[j*3+1], nz = cb[j*3+2];
    float d  = knn_dist[(size_t)b * Nc * Kc + r];
    float geo[10] = {cx,cy,cz,nx,ny,nz,cx-nx,cy-ny,cz-nz,d};

    #pragma unroll
    for (int g = 0; g < 16; g++) {
        float s = 0.f, q = 0.f;
        #pragma unroll
        for (int oo = 0; oo < 8; oo++) {
            int o = g * 8 + oo;
            float y = bl[o];
            #pragma unroll
            for (int c = 0; c < 10; c++) y += wl[o*10+c] * geo[c];
            s += y; q += y * y;
        }
        atomicAdd(&sstat[g*2+0], s);
        atomicAdd(&sstat[g*2+1], q);
    }
    __syncthreads();
    if (tid < 32) atomicAdd(&stats[b * 32 + tid], sstat[tid]);
}

// LSE pooled-m: per 16-point tile, recompute geo conv, apply GN+relu, mean
// over K -> m[b][0:128][n]; gather-mean of xprev over idx -> m[b][128:256][n].
__launch_bounds__(256)
__global__ void lse_m_kernel(const float* __restrict__ coords,
                             const int* __restrict__ knn_idx,
                             const float* __restrict__ knn_dist,
                             const float* __restrict__ xprev,   // [b][128][N]
                             const float* __restrict__ w,       // [128][10]
                             const float* __restrict__ bias,
                             const float* __restrict__ gw,
                             const float* __restrict__ gb,
                             const float* __restrict__ stats,   // [B][16][2]
                             float cnt,
                             float* __restrict__ m)             // [b][256][N]
{
    __shared__ float wl[1280];
    __shared__ float bl[128], gwl[128], gbl[128];
    __shared__ float smean[16], sinv[16];
    __shared__ float geo_t[160 * 16];   // [k][c][tp] — tp innermost: conflict-free reads
    __shared__ int   jl[16 * 16];       // [k][tp]
    int tid = threadIdx.x;
    int nt  = Nc / 16;
    int b   = blockIdx.x / nt;
    int n0  = (blockIdx.x % nt) * 16;

    for (int e = tid; e < 1280; e += 256) wl[e] = w[e];
    if (tid < 128) { bl[tid] = bias[tid]; gwl[tid] = gw[tid]; gbl[tid] = gb[tid]; }
    if (tid < 16) {
        float s0 = stats[(b*16+tid)*2+0], s1 = stats[(b*16+tid)*2+1];
        float mean = s0 / cnt;
        float var  = s1 / cnt - mean * mean;
        smean[tid] = mean;
        sinv[tid]  = rsqrtf(var + EPSc);
    }
    {   // phase 1: geo features for the 16x16 (point,k) tile
        int tp = tid & 15, k = tid >> 4;
        int n  = n0 + tp;
        const float* cb = coords + (size_t)b * Nc * 3;
        float cx = cb[n*3+0], cy = cb[n*3+1], cz = cb[n*3+2];
        int   j  = knn_idx[((size_t)b*Nc + n)*Kc + k];
        float nx = cb[j*3+0], ny = cb[j*3+1], nz = cb[j*3+2];
        float d  = knn_dist[((size_t)b*Nc + n)*Kc + k];
        float geo[10] = {cx,cy,cz,nx,ny,nz,cx-nx,cy-ny,cz-nz,d};
        #pragma unroll
        for (int c = 0; c < 10; c++) geo_t[(k*10+c)*16 + tp] = geo[c];
        jl[k*16 + tp] = j;
    }
    __syncthreads();
    {   // phase 2: geo conv -> GN -> relu -> mean over K
        int tp = tid & 15, oh = tid >> 4;
        #pragma unroll
        for (int j8 = 0; j8 < 8; j8++) {
            int o = oh * 8 + j8;
            int g = o >> 3;
            float mu = smean[g], iv = sinv[g];
            float gwo = gwl[o], gbo = gbl[o], bo = bl[o];
            float acc = 0.f;
            #pragma unroll 4
            for (int k = 0; k < 16; k++) {
                float y = bo;
                #pragma unroll
                for (int c = 0; c < 10; c++) y += wl[o*10+c] * geo_t[(k*10+c)*16 + tp];
                float v = (y - mu) * iv * gwo + gbo;
                acc += v > 0.f ? v : 0.f;
            }
            m[((size_t)b*256 + o)*Nc + n0 + tp] = acc * (1.f/16.f);
        }
    }
    {   // phase 3: neighbor-feature gather mean
        int tp = tid & 15, chh = tid >> 4;
        #pragma unroll
        for (int j8 = 0; j8 < 8; j8++) {
            int c = chh * 8 + j8;
            const float* xb = xprev + ((size_t)b*128 + c)*Nc;
            float acc = 0.f;
            #pragma unroll
            for (int k = 0; k < 16; k++) acc += xb[jl[k*16 + tp]];
            m[((size_t)b*256 + 128 + c)*Nc + n0 + tp] = acc * (1.f/16.f);
        }
    }
}

// Elementwise GN + relu, in place.
template<int C, int GROUP_CH>
__launch_bounds__(256)
__global__ void gn_relu_kernel(float* __restrict__ z,
                               const float* __restrict__ stats,
                               const float* __restrict__ gw,
                               const float* __restrict__ gb,
                               float cnt)
{
    size_t i = (size_t)blockIdx.x * 256 + threadIdx.x;
    if (i >= (size_t)Bc * C * Nc) return;
    int c = (int)((i / Nc) % C);
    int b = (int)(i / ((size_t)C * Nc));
    int g = c / GROUP_CH;
    float s0 = stats[(b * 16 + g) * 2 + 0];
    float s1 = stats[(b * 16 + g) * 2 + 1];
    float mean = s0 / cnt;
    float var  = s1 / cnt - mean * mean;
    float inv  = rsqrtf(var + EPSc);
    float v = (z[i] - mean) * inv * gw[c] + gb[c];
    z[i] = v > 0.f ? v : 0.f;
}

extern "C" void kernel_launch(void* const* d_in, const int* in_sizes, int n_in,
                              void* d_out, int out_size, void* d_ws, size_t ws_size,
                              hipStream_t stream)
{
    const float* coords   = (const float*)d_in[0];
    const float* features = (const float*)d_in[1];
    const float* knn_dist = (const float*)d_in[2];
    const int*   knn_idx  = (const int*)  d_in[3];
    const float* w1       = (const float*)d_in[4];
    const float* b1       = (const float*)d_in[5];
    const float* lse1_w   = (const float*)d_in[6];
    const float* lse1_b   = (const float*)d_in[7];
    const float* lse1_gw  = (const float*)d_in[8];
    const float* lse1_gb  = (const float*)d_in[9];
    const float* pool1_w  = (const float*)d_in[10];
    const float* pool1_b  = (const float*)d_in[11];
    const float* pool1_gw = (const float*)d_in[12];
    const float* pool1_gb = (const float*)d_in[13];
    const float* lse2_w   = (const float*)d_in[14];
    const float* lse2_b   = (const float*)d_in[15];
    const float* lse2_gw  = (const float*)d_in[16];
    const float* lse2_gb  = (const float*)d_in[17];
    const float* pool2_w  = (const float*)d_in[18];
    const float* pool2_b  = (const float*)d_in[19];
    const float* pool2_gw = (const float*)d_in[20];
    const float* pool2_gb = (const float*)d_in[21];
    const float* mlp2_w   = (const float*)d_in[22];
    const float* mlp2_b   = (const float*)d_in[23];
    const float* sc_w     = (const float*)d_in[24];
    const float* sc_b     = (const float*)d_in[25];
    const float* sc_gw    = (const float*)d_in[26];
    const float* sc_gb    = (const float*)d_in[27];
    (void)in_sizes; (void)n_in; (void)out_size; (void)ws_size;

    float* ws = (float*)d_ws;
    float* S  = ws + OFF_S;
    float* X1 = ws + OFF_X1;
    float* M  = ws + OFF_M;
    float* Z  = ws + OFF_Z;
    float* ST = ws + OFF_ST;
    float* ST_SC = ST +   0;
    float* ST_L1 = ST +  64;
    float* ST_P1 = ST + 128;
    float* ST_L2 = ST + 192;
    float* ST_P2 = ST + 256;
    float* out = (float*)d_out;

    zero_kernel<<<2, 256, 0, stream>>>(ST, 512);

    // shortcut conv + stats: features(128) -> S(512), group=32ch
    conv_kernel<128,512,32,2,64><<<Bc*Nc/64, 256, 0, stream>>>(
        features, sc_w, sc_b, S, ST_SC, nullptr, nullptr, nullptr, nullptr, 0.f);
    // mlp1: features(128) -> X1(128), leaky 0.2
    conv_kernel<128,128,8,1,64><<<Bc*Nc/64, 256, 0, stream>>>(
        features, w1, b1, X1, nullptr, nullptr, nullptr, nullptr, nullptr, 0.f);
    // lse1
    lse_stats_kernel<<<Bc*Nc*Kc/256, 256, 0, stream>>>(
        coords, knn_idx, knn_dist, lse1_w, lse1_b, ST_L1);
    lse_m_kernel<<<Bc*Nc/16, 256, 0, stream>>>(
        coords, knn_idx, knn_dist, X1, lse1_w, lse1_b, lse1_gw, lse1_gb,
        ST_L1, (float)(8.0 * Nc * Kc), M);
    // pool1: M(256) -> Z(128) + stats, group=8ch
    conv_kernel<256,128,8,2,32><<<Bc*Nc/32, 256, 0, stream>>>(
        M, pool1_w, pool1_b, Z, ST_P1, nullptr, nullptr, nullptr, nullptr, 0.f);
    gn_relu_kernel<128,8><<<(Bc*128*Nc)/256, 256, 0, stream>>>(
        Z, ST_P1, pool1_gw, pool1_gb, (float)(8 * Nc));
    // lse2 (xprev = Z, i.e. x2)
    lse_stats_kernel<<<Bc*Nc*Kc/256, 256, 0, stream>>>(
        coords, knn_idx, knn_dist, lse2_w, lse2_b, ST_L2);
    lse_m_kernel<<<Bc*Nc/16, 256, 0, stream>>>(
        coords, knn_idx, knn_dist, Z, lse2_w, lse2_b, lse2_gw, lse2_gb,
        ST_L2, (float)(8.0 * Nc * Kc), M);
    // pool2: M(256) -> Z(256) + stats, group=16ch
    conv_kernel<256,256,16,2,32><<<Bc*Nc/32, 256, 0, stream>>>(
        M, pool2_w, pool2_b, Z, ST_P2, nullptr, nullptr, nullptr, nullptr, 0.f);
    gn_relu_kernel<256,16><<<(Bc*256*Nc)/256, 256, 0, stream>>>(
        Z, ST_P2, pool2_gw, pool2_gb, (float)(16 * Nc));
    // final: mlp2(Z 256 -> 512) + GN(S) -> leaky 0.01 -> out
    conv_kernel<256,512,32,3,32><<<Bc*Nc/32, 256, 0, stream>>>(
        Z, mlp2_w, mlp2_b, out, nullptr, S, ST_SC, sc_gw, sc_gb, (float)(32 * Nc));
}

// Round 2
// 1123.769 us; speedup vs baseline: 2.0909x; 2.0909x over previous
//
#include <hip/hip_runtime.h>

// LocalFeatureAggregation — bf16-MFMA pipeline.
// B=2, N=16384, K=16, D_IN=128, D_OUT=256, GROUPS=16.
//
// All dense 1x1 convs run as bf16 MFMA GEMMs (16x16x32, f32 accum).
// GN stats are accumulated from the unrounded f32 accumulators (MODE 2),
// activations stored bf16, normalize passes read/write bf16.
// lse geo conv (10-wide) stays f32 vector; neighbor gather reads bf16.

constexpr int Bc = 2;
constexpr int Nc = 16384;
constexpr int Kc = 16;
constexpr float EPSc = 1e-6f;

typedef __attribute__((ext_vector_type(8))) short short8;
typedef __attribute__((ext_vector_type(4))) float floatx4;

__device__ inline short f2bf(float x) {
    union { float f; unsigned u; } v; v.f = x;
    unsigned r = v.u + 0x7fffu + ((v.u >> 16) & 1u);
    return (short)(r >> 16);
}
__device__ inline float bf2f(short s) {
    union { unsigned u; float f; } v;
    v.u = ((unsigned)(unsigned short)s) << 16;
    return v.f;
}

// ---- workspace layout ----
// ws[0..511]            : f32 stats (5 sets of 32, padded)
// then bf16 (short) region, offsets in shorts:
constexpr size_t OW_W1  = 0;                       // 128*128
constexpr size_t OW_P1W = OW_W1  + 128*128;        // 128*256
constexpr size_t OW_P2W = OW_P1W + 128*256;        // 256*256
constexpr size_t OW_M2W = OW_P2W + 256*256;        // 512*256
constexpr size_t OW_SCW = OW_M2W + 512*256;        // 512*128
constexpr size_t OW_FB  = OW_SCW + 512*128;        // 2*128*Nc
constexpr size_t OW_X1  = OW_FB  + (size_t)Bc*128*Nc;
constexpr size_t OW_M   = OW_X1  + (size_t)Bc*128*Nc;
constexpr size_t OW_Z1  = OW_M   + (size_t)Bc*256*Nc;
constexpr size_t OW_Z2  = OW_Z1  + (size_t)Bc*128*Nc;
constexpr size_t OW_S   = OW_Z2  + (size_t)Bc*256*Nc;

__global__ void zero_kernel(float* __restrict__ p, int n) {
    int i = blockIdx.x * 256 + threadIdx.x;
    if (i < n) p[i] = 0.f;
}

__global__ void cvt_kernel(const float* __restrict__ src, short* __restrict__ dst, int n) {
    int i = blockIdx.x * 256 + threadIdx.x;
    if (i < n) dst[i] = f2bf(src[i]);
}

// GEMM: out[b][o][n] = sum_c W[o][c] * X[b][c][n] + bias[o]
// MODE 1: leaky 0.2 -> bf16 out
// MODE 2: raw bf16 out + per-group sum/sumsq (f32) -> stats atomics
// MODE 3: v + GN(sbuf) -> leaky 0.01 -> f32 out
template<int CIN, int COUT, int GROUP_CH, int MODE>
__launch_bounds__(256)
__global__ void gemm_conv(const short* __restrict__ wA,   // [COUT][CIN] bf16
                          const short* __restrict__ xB,   // [b][CIN][Nc] bf16
                          const float* __restrict__ bias,
                          short* __restrict__ outb,
                          float* __restrict__ outf,
                          float* __restrict__ stats,
                          const short* __restrict__ sbuf, // [b][512][Nc] bf16 raw
                          const float* __restrict__ st_sc,
                          const float* __restrict__ gw,
                          const float* __restrict__ gb,
                          float sc_cnt)
{
    __shared__ short Abuf[128 * 40];
    __shared__ short Bbuf[128 * 40];
    __shared__ float sstat[32];
    __shared__ float smean[4], sinv[4];

    const int tid  = threadIdx.x;
    const int n0   = blockIdx.x * 128;
    const int mo   = blockIdx.y * 128;
    const int b    = blockIdx.z;
    const int lane = tid & 63;
    const int wave = tid >> 6;
    const int wm   = (wave >> 1) * 64;
    const int wn   = (wave & 1) * 64;
    const int l15  = lane & 15;
    const int quad = lane >> 4;

    if constexpr (MODE == 2) { if (tid < 32) sstat[tid] = 0.f; }
    if constexpr (MODE == 3) {
        if (tid < 4) {
            int g = (mo >> 5) + tid;
            float s0 = st_sc[(b * 16 + g) * 2 + 0];
            float s1 = st_sc[(b * 16 + g) * 2 + 1];
            float mean = s0 / sc_cnt;
            float var  = s1 / sc_cnt - mean * mean;
            smean[tid] = mean;
            sinv[tid]  = rsqrtf(var + EPSc);
        }
    }

    floatx4 acc[4][4];
    #pragma unroll
    for (int mi = 0; mi < 4; mi++)
        #pragma unroll
        for (int ni = 0; ni < 4; ni++)
            acc[mi][ni] = (floatx4){0.f, 0.f, 0.f, 0.f};

    const short* wAr = wA + (size_t)mo * CIN;
    const short* xBr = xB + (size_t)b * CIN * Nc + n0;

    for (int c0 = 0; c0 < CIN; c0 += 32) {
        __syncthreads();
        // stage A (weights): [128 rows][32 k], b128 chunks
        #pragma unroll
        for (int s = 0; s < 2; s++) {
            int e = tid + s * 256;
            int r = e >> 2, q = e & 3;
            *(short8*)&Abuf[r * 40 + q * 8] =
                *(const short8*)(wAr + (size_t)r * CIN + c0 + q * 8);
        }
        // stage B (input, transposed to [n][k])
        #pragma unroll
        for (int s = 0; s < 2; s++) {
            int e = tid + s * 256;
            int kl = e >> 4, n8 = e & 15;
            short8 v = *(const short8*)(xBr + (size_t)(c0 + kl) * Nc + n8 * 8);
            #pragma unroll
            for (int i = 0; i < 8; i++) Bbuf[(n8 * 8 + i) * 40 + kl] = v[i];
        }
        __syncthreads();

        short8 af[4], bfr[4];
        #pragma unroll
        for (int mi = 0; mi < 4; mi++)
            af[mi] = *(short8*)&Abuf[(wm + mi * 16 + l15) * 40 + quad * 8];
        #pragma unroll
        for (int ni = 0; ni < 4; ni++)
            bfr[ni] = *(short8*)&Bbuf[(wn + ni * 16 + l15) * 40 + quad * 8];
        #pragma unroll
        for (int mi = 0; mi < 4; mi++)
            #pragma unroll
            for (int ni = 0; ni < 4; ni++)
                acc[mi][ni] = __builtin_amdgcn_mfma_f32_16x16x32_bf16(
                    af[mi], bfr[ni], acc[mi][ni], 0, 0, 0);
    }

    // epilogue: D row = mo+wm+mi*16+quad*4+r, col = n0+wn+ni*16+l15
    #pragma unroll
    for (int mi = 0; mi < 4; mi++) {
        int rowl = wm + mi * 16 + quad * 4;
        float b4[4], gw4[4], gb4[4];
        #pragma unroll
        for (int r = 0; r < 4; r++) {
            b4[r] = bias[mo + rowl + r];
            if constexpr (MODE == 3) {
                gw4[r] = gw[mo + rowl + r];
                gb4[r] = gb[mo + rowl + r];
            }
        }
        float gs = 0.f, gq = 0.f;
        #pragma unroll
        for (int ni = 0; ni < 4; ni++) {
            int col = n0 + wn + ni * 16 + l15;
            #pragma unroll
            for (int r = 0; r < 4; r++) {
                int row = mo + rowl + r;
                float v = acc[mi][ni][r] + b4[r];
                if constexpr (MODE == 1) {
                    v = v > 0.f ? v : 0.2f * v;
                    outb[((size_t)b * COUT + row) * Nc + col] = f2bf(v);
                } else if constexpr (MODE == 2) {
                    gs += v; gq += v * v;
                    outb[((size_t)b * COUT + row) * Nc + col] = f2bf(v);
                } else {
                    int gl = rowl >> 5;
                    float s = bf2f(sbuf[((size_t)b * 512 + row) * Nc + col]);
                    float sn = (s - smean[gl]) * sinv[gl] * gw4[r] + gb4[r];
                    float o = v + sn;
                    o = o > 0.f ? o : 0.01f * o;
                    outf[((size_t)b * COUT + row) * Nc + col] = o;
                }
            }
        }
        if constexpr (MODE == 2) {
            // 16 lanes (same quad) share the same group: butterfly then 1 atomic
            #pragma unroll
            for (int off = 1; off < 16; off <<= 1) {
                gs += __shfl_xor(gs, off);
                gq += __shfl_xor(gq, off);
            }
            if (l15 == 0) {
                int gl = rowl / GROUP_CH;
                atomicAdd(&sstat[gl * 2 + 0], gs);
                atomicAdd(&sstat[gl * 2 + 1], gq);
            }
        }
    }
    if constexpr (MODE == 2) {
        __syncthreads();
        constexpr int NG = 128 / GROUP_CH;
        if (tid < 2 * NG) {
            int g0 = mo / GROUP_CH;
            atomicAdd(&stats[b * 32 + (g0 + (tid >> 1)) * 2 + (tid & 1)], sstat[tid]);
        }
    }
}

// LSE geo-conv stats: one thread per (b,n,k); recompute y[o] for all 128 o,
// reduce sum/sumsq per group via LDS + global atomics. (f32)
__launch_bounds__(256)
__global__ void lse_stats_kernel(const float* __restrict__ coords,
                                 const int* __restrict__ knn_idx,
                                 const float* __restrict__ knn_dist,
                                 const float* __restrict__ w,     // [128][10]
                                 const float* __restrict__ bias,  // [128]
                                 float* __restrict__ stats)       // [B][16][2]
{
    __shared__ float wl[1280];
    __shared__ float bl[128];
    __shared__ float sstat[32];
    int tid = threadIdx.x;
    for (int e = tid; e < 1280; e += 256) wl[e] = w[e];
    if (tid < 128) bl[tid] = bias[tid];
    if (tid < 32)  sstat[tid] = 0.f;
    __syncthreads();

    int gt = blockIdx.x * 256 + tid;
    int b  = gt / (Nc * Kc);
    int r  = gt % (Nc * Kc);
    int n  = r / Kc;
    const float* cb = coords + (size_t)b * Nc * 3;
    float cx = cb[n*3+0], cy = cb[n*3+1], cz = cb[n*3+2];
    int   j  = knn_idx[(size_t)b * Nc * Kc + r];
    float nx = cb[j*3+0], ny = cb[j*3+1], nz = cb[j*3+2];
    float d  = knn_dist[(size_t)b * Nc * Kc + r];
    float geo[10] = {cx,cy,cz,nx,ny,nz,cx-nx,cy-ny,cz-nz,d};

    #pragma unroll
    for (int g = 0; g < 16; g++) {
        float s = 0.f, q = 0.f;
        #pragma unroll
        for (int oo = 0; oo < 8; oo++) {
            int o = g * 8 + oo;
            float y = bl[o];
            #pragma unroll
            for (int c = 0; c < 10; c++) y += wl[o*10+c] * geo[c];
            s += y; q += y * y;
        }
        atomicAdd(&sstat[g*2+0], s);
        atomicAdd(&sstat[g*2+1], q);
    }
    __syncthreads();
    if (tid < 32) atomicAdd(&stats[b * 32 + tid], sstat[tid]);
}

// LSE pooled-m: recompute geo conv, GN+relu, mean over K -> m[0:128];
// gather-mean of bf16 xprev -> m[128:256]. m is bf16.
__launch_bounds__(256)
__global__ void lse_m_kernel(const float* __restrict__ coords,
                             const int* __restrict__ knn_idx,
                             const float* __restrict__ knn_dist,
                             const short* __restrict__ xprev,   // [b][128][Nc] bf16
                             const float* __restrict__ w,       // [128][10]
                             const float* __restrict__ bias,
                             const float* __restrict__ gw,
                             const float* __restrict__ gb,
                             const float* __restrict__ stats,   // [B][16][2]
                             float cnt,
                             short* __restrict__ m)             // [b][256][Nc] bf16
{
    __shared__ float wl[1280];
    __shared__ float bl[128], gwl[128], gbl[128];
    __shared__ float smean[16], sinv[16];
    __shared__ float geo_t[160 * 16];
    __shared__ int   jl[16 * 16];
    int tid = threadIdx.x;
    int nt  = Nc / 16;
    int b   = blockIdx.x / nt;
    int n0  = (blockIdx.x % nt) * 16;

    for (int e = tid; e < 1280; e += 256) wl[e] = w[e];
    if (tid < 128) { bl[tid] = bias[tid]; gwl[tid] = gw[tid]; gbl[tid] = gb[tid]; }
    if (tid < 16) {
        float s0 = stats[(b*16+tid)*2+0], s1 = stats[(b*16+tid)*2+1];
        float mean = s0 / cnt;
        float var  = s1 / cnt - mean * mean;
        smean[tid] = mean;
        sinv[tid]  = rsqrtf(var + EPSc);
    }
    {
        int tp = tid & 15, k = tid >> 4;
        int n  = n0 + tp;
        const float* cb = coords + (size_t)b * Nc * 3;
        float cx = cb[n*3+0], cy = cb[n*3+1], cz = cb[n*3+2];
        int   j  = knn_idx[((size_t)b*Nc + n)*Kc + k];
        float nx = cb[j*3+0], ny = cb[j*3+1], nz = cb[j*3+2];
        float d  = knn_dist[((size_t)b*Nc + n)*Kc + k];
        float geo[10] = {cx,cy,cz,nx,ny,nz,cx-nx,cy-ny,cz-nz,d};
        #pragma unroll
        for (int c = 0; c < 10; c++) geo_t[(k*10+c)*16 + tp] = geo[c];
        jl[k*16 + tp] = j;
    }
    __syncthreads();
    {
        int tp = tid & 15, oh = tid >> 4;
        #pragma unroll
        for (int j8 = 0; j8 < 8; j8++) {
            int o = oh * 8 + j8;
            int g = o >> 3;
            float mu = smean[g], iv = sinv[g];
            float gwo = gwl[o], gbo = gbl[o], bo = bl[o];
            float acc = 0.f;
            #pragma unroll 4
            for (int k = 0; k < 16; k++) {
                float y = bo;
                #pragma unroll
                for (int c = 0; c < 10; c++) y += wl[o*10+c] * geo_t[(k*10+c)*16 + tp];
                float v = (y - mu) * iv * gwo + gbo;
                acc += v > 0.f ? v : 0.f;
            }
            m[((size_t)b*256 + o)*Nc + n0 + tp] = f2bf(acc * (1.f/16.f));
        }
    }
    {
        int tp = tid & 15, chh = tid >> 4;
        #pragma unroll
        for (int j8 = 0; j8 < 8; j8++) {
            int c = chh * 8 + j8;
            const short* xb = xprev + ((size_t)b*128 + c)*Nc;
            float acc = 0.f;
            #pragma unroll
            for (int k = 0; k < 16; k++) acc += bf2f(xb[jl[k*16 + tp]]);
            m[((size_t)b*256 + 128 + c)*Nc + n0 + tp] = f2bf(acc * (1.f/16.f));
        }
    }
}

// Elementwise GN + relu on bf16, in place.
template<int C, int GROUP_CH>
__launch_bounds__(256)
__global__ void gn_relu_kernel(short* __restrict__ z,
                               const float* __restrict__ stats,
                               const float* __restrict__ gw,
                               const float* __restrict__ gb,
                               float cnt)
{
    size_t i = (size_t)blockIdx.x * 256 + threadIdx.x;
    if (i >= (size_t)Bc * C * Nc) return;
    int c = (int)((i / Nc) % C);
    int b = (int)(i / ((size_t)C * Nc));
    int g = c / GROUP_CH;
    float s0 = stats[(b * 16 + g) * 2 + 0];
    float s1 = stats[(b * 16 + g) * 2 + 1];
    float mean = s0 / cnt;
    float var  = s1 / cnt - mean * mean;
    float inv  = rsqrtf(var + EPSc);
    float v = (bf2f(z[i]) - mean) * inv * gw[c] + gb[c];
    z[i] = f2bf(v > 0.f ? v : 0.f);
}

extern "C" void kernel_launch(void* const* d_in, const int* in_sizes, int n_in,
                              void* d_out, int out_size, void* d_ws, size_t ws_size,
                              hipStream_t stream)
{
    const float* coords   = (const float*)d_in[0];
    const float* features = (const float*)d_in[1];
    const float* knn_dist = (const float*)d_in[2];
    const int*   knn_idx  = (const int*)  d_in[3];
    const float* w1       = (const float*)d_in[4];
    const float* b1       = (const float*)d_in[5];
    const float* lse1_w   = (const float*)d_in[6];
    const float* lse1_b   = (const float*)d_in[7];
    const float* lse1_gw  = (const float*)d_in[8];
    const float* lse1_gb  = (const float*)d_in[9];
    const float* pool1_w  = (const float*)d_in[10];
    const float* pool1_b  = (const float*)d_in[11];
    const float* pool1_gw = (const float*)d_in[12];
    const float* pool1_gb = (const float*)d_in[13];
    const float* lse2_w   = (const float*)d_in[14];
    const float* lse2_b   = (const float*)d_in[15];
    const float* lse2_gw  = (const float*)d_in[16];
    const float* lse2_gb  = (const float*)d_in[17];
    const float* pool2_w  = (const float*)d_in[18];
    const float* pool2_b  = (const float*)d_in[19];
    const float* pool2_gw = (const float*)d_in[20];
    const float* pool2_gb = (const float*)d_in[21];
    const float* mlp2_w   = (const float*)d_in[22];
    const float* mlp2_b   = (const float*)d_in[23];
    const float* sc_w     = (const float*)d_in[24];
    const float* sc_b     = (const float*)d_in[25];
    const float* sc_gw    = (const float*)d_in[26];
    const float* sc_gb    = (const float*)d_in[27];
    (void)in_sizes; (void)n_in; (void)out_size; (void)ws_size;

    float* ST = (float*)d_ws;           // 512 floats
    float* ST_SC = ST +   0;
    float* ST_L1 = ST +  64;
    float* ST_P1 = ST + 128;
    float* ST_L2 = ST + 192;
    float* ST_P2 = ST + 256;
    short* W16 = (short*)(ST + 512);
    short* W1b  = W16 + OW_W1;
    short* P1Wb = W16 + OW_P1W;
    short* P2Wb = W16 + OW_P2W;
    short* M2Wb = W16 + OW_M2W;
    short* SCWb = W16 + OW_SCW;
    short* FB   = W16 + OW_FB;
    short* X1B  = W16 + OW_X1;
    short* MB   = W16 + OW_M;
    short* Z1   = W16 + OW_Z1;
    short* Z2   = W16 + OW_Z2;
    short* SB   = W16 + OW_S;
    float* out  = (float*)d_out;

    zero_kernel<<<2, 256, 0, stream>>>(ST, 512);

    cvt_kernel<<<(128*128+255)/256, 256, 0, stream>>>(w1, W1b, 128*128);
    cvt_kernel<<<(128*256+255)/256, 256, 0, stream>>>(pool1_w, P1Wb, 128*256);
    cvt_kernel<<<(256*256+255)/256, 256, 0, stream>>>(pool2_w, P2Wb, 256*256);
    cvt_kernel<<<(512*256+255)/256, 256, 0, stream>>>(mlp2_w, M2Wb, 512*256);
    cvt_kernel<<<(512*128+255)/256, 256, 0, stream>>>(sc_w, SCWb, 512*128);
    cvt_kernel<<<(Bc*128*Nc+255)/256, 256, 0, stream>>>(features, FB, Bc*128*Nc);

    // sc: 128 -> 512, raw bf16 S + stats (group=32ch)
    gemm_conv<128,512,32,2><<<dim3(Nc/128, 4, Bc), 256, 0, stream>>>(
        SCWb, FB, sc_b, SB, nullptr, ST_SC, nullptr, nullptr, nullptr, nullptr, 0.f);
    // mlp1: 128 -> 128, leaky 0.2
    gemm_conv<128,128,8,1><<<dim3(Nc/128, 1, Bc), 256, 0, stream>>>(
        W1b, FB, b1, X1B, nullptr, nullptr, nullptr, nullptr, nullptr, nullptr, 0.f);
    // lse1
    lse_stats_kernel<<<Bc*Nc*Kc/256, 256, 0, stream>>>(
        coords, knn_idx, knn_dist, lse1_w, lse1_b, ST_L1);
    lse_m_kernel<<<Bc*Nc/16, 256, 0, stream>>>(
        coords, knn_idx, knn_dist, X1B, lse1_w, lse1_b, lse1_gw, lse1_gb,
        ST_L1, (float)(8.0 * Nc * Kc), MB);
    // pool1: 256 -> 128 + stats (group=8ch)
    gemm_conv<256,128,8,2><<<dim3(Nc/128, 1, Bc), 256, 0, stream>>>(
        P1Wb, MB, pool1_b, Z1, nullptr, ST_P1, nullptr, nullptr, nullptr, nullptr, 0.f);
    gn_relu_kernel<128,8><<<(Bc*128*Nc)/256, 256, 0, stream>>>(
        Z1, ST_P1, pool1_gw, pool1_gb, (float)(8 * Nc));
    // lse2
    lse_stats_kernel<<<Bc*Nc*Kc/256, 256, 0, stream>>>(
        coords, knn_idx, knn_dist, lse2_w, lse2_b, ST_L2);
    lse_m_kernel<<<Bc*Nc/16, 256, 0, stream>>>(
        coords, knn_idx, knn_dist, Z1, lse2_w, lse2_b, lse2_gw, lse2_gb,
        ST_L2, (float)(8.0 * Nc * Kc), MB);
    // pool2: 256 -> 256 + stats (group=16ch)
    gemm_conv<256,256,16,2><<<dim3(Nc/128, 2, Bc), 256, 0, stream>>>(
        P2Wb, MB, pool2_b, Z2, nullptr, ST_P2, nullptr, nullptr, nullptr, nullptr, 0.f);
    gn_relu_kernel<256,16><<<(Bc*256*Nc)/256, 256, 0, stream>>>(
        Z2, ST_P2, pool2_gw, pool2_gb, (float)(16 * Nc));
    // final: mlp2(x3) + GN(S) -> leaky 0.01 -> f32 out
    gemm_conv<256,512,32,3><<<dim3(Nc/128, 4, Bc), 256, 0, stream>>>(
        M2Wb, Z2, mlp2_b, nullptr, out, nullptr, SB, ST_SC, sc_gw, sc_gb,
        (float)(32 * Nc));
}

// Round 3
// 388.776 us; speedup vs baseline: 6.0438x; 2.8905x over previous
//
#include <hip/hip_runtime.h>

// LocalFeatureAggregation — bf16-MFMA pipeline, point-major activations.
// B=2, N=16384, K=16, D_IN=128, D_OUT=256, GROUPS=16.
//
// All activations are [b][N][C] bf16 (point-major): GEMM A/B operands are both
// K-major (b128 staging, no LDS transpose), the LSE neighbor gather reads
// contiguous 256B rows, epilogue stores are b64/b128.
// LSE geo conv runs as MFMA (K padded 10->32). LSE GN stats come from the
// closed form: sum_y = NK*b + w.S, sum_y2 = NK*b^2 + 2b(w.S) + w^T Q w where
// S (10) and Q (55 upper-tri) are reduced once by geo_reduce (weight-indep).

constexpr int Bc = 2;
constexpr int Nc = 16384;
constexpr int Kc = 16;
constexpr float EPSc = 1e-6f;

typedef __attribute__((ext_vector_type(8))) short short8;
typedef __attribute__((ext_vector_type(4))) short short4v;
typedef __attribute__((ext_vector_type(4))) float floatx4;

__device__ inline short f2bf(float x) {
    union { float f; unsigned u; } v; v.f = x;
    unsigned r = v.u + 0x7fffu + ((v.u >> 16) & 1u);
    return (short)(r >> 16);
}
__device__ inline float bf2f(short s) {
    union { unsigned u; float f; } v;
    v.u = ((unsigned)(unsigned short)s) << 16;
    return v.f;
}

// ---- workspace layout ----
// f32 ST[1024]: ST_SC=0, ST_P1=64, ST_P2=128, ST_GEO=256 (B x 65)
// then bf16 (short) region, offsets in shorts:
constexpr size_t OW_W1  = 0;                        // 128*128
constexpr size_t OW_P1W = OW_W1  + 128*128;         // 128*256
constexpr size_t OW_P2W = OW_P1W + 128*256;         // 256*256
constexpr size_t OW_M2W = OW_P2W + 256*256;         // 512*256
constexpr size_t OW_SCW = OW_M2W + 512*256;         // 512*128
constexpr size_t OW_L1W = OW_SCW + 512*128;         // 128*32 (K padded)
constexpr size_t OW_L2W = OW_L1W + 128*32;          // 128*32
constexpr size_t OW_FB  = OW_L2W + 128*32;          // B*N*128
constexpr size_t OW_X1  = OW_FB  + (size_t)Bc*Nc*128;
constexpr size_t OW_M   = OW_X1  + (size_t)Bc*Nc*128;
constexpr size_t OW_Z1  = OW_M   + (size_t)Bc*Nc*256;
constexpr size_t OW_Z2  = OW_Z1  + (size_t)Bc*Nc*128;
constexpr size_t OW_S   = OW_Z2  + (size_t)Bc*Nc*256;

__global__ void zero_kernel(float* __restrict__ p, int n) {
    int i = blockIdx.x * 256 + threadIdx.x;
    if (i < n) p[i] = 0.f;
}

__global__ void cvt_kernel(const float* __restrict__ src, short* __restrict__ dst, int n) {
    int i = blockIdx.x * 256 + threadIdx.x;
    if (i < n) dst[i] = f2bf(src[i]);
}

// lse weight [128][10] f32 -> [128][32] bf16 zero-padded
__global__ void cvt_pad_kernel(const float* __restrict__ src, short* __restrict__ dst) {
    int i = blockIdx.x * 256 + threadIdx.x;   // 4096
    int o = i >> 5, c = i & 31;
    dst[i] = (c < 10) ? f2bf(src[o * 10 + c]) : (short)0;
}

// features f32 [b][128][N] -> FB bf16 [b][N][128]
__global__ void feat_t_kernel(const float* __restrict__ in, short* __restrict__ out) {
    int tid  = threadIdx.x;
    int lane = tid & 63, wave = tid >> 6;
    int bb = blockIdx.x / (Nc / 64);
    int n  = (blockIdx.x % (Nc / 64)) * 64 + lane;
    #pragma unroll
    for (int cc = 0; cc < 4; cc++) {
        int c0 = (wave + cc * 4) * 8;
        short8 sv;
        #pragma unroll
        for (int i = 0; i < 8; i++)
            sv[i] = f2bf(in[((size_t)bb * 128 + c0 + i) * Nc + n]);
        *(short8*)&out[((size_t)(bb * Nc + n)) * 128 + c0] = sv;
    }
}

// Reduce S (10) and Q upper-tri (55) of geo over all (n,k), per batch.
__launch_bounds__(256)
__global__ void geo_reduce_kernel(const float* __restrict__ coords,
                                  const int* __restrict__ knn_idx,
                                  const float* __restrict__ knn_dist,
                                  float* __restrict__ dst)   // [B][65]
{
    __shared__ float part[4][65];
    int tid = threadIdx.x;
    int gt  = blockIdx.x * 256 + tid;
    int b   = gt >> 18;              // N*K = 2^18
    int r   = gt & (Nc * Kc - 1);
    int n   = r >> 4;
    const float* cb = coords + (size_t)b * Nc * 3;
    float cx = cb[n*3+0], cy = cb[n*3+1], cz = cb[n*3+2];
    int   j  = knn_idx[(size_t)b * Nc * Kc + r];
    float nx = cb[j*3+0], ny = cb[j*3+1], nz = cb[j*3+2];
    float d  = knn_dist[(size_t)b * Nc * Kc + r];
    float g[10] = {cx,cy,cz,nx,ny,nz,cx-nx,cy-ny,cz-nz,d};

    float vals[65];
    #pragma unroll
    for (int c = 0; c < 10; c++) vals[c] = g[c];
    {
        int idx = 10;
        #pragma unroll
        for (int c = 0; c < 10; c++)
            #pragma unroll
            for (int c2 = c; c2 < 10; c2++) vals[idx++] = g[c] * g[c2];
    }
    #pragma unroll
    for (int i = 0; i < 65; i++) {
        float v = vals[i];
        #pragma unroll
        for (int off = 1; off < 64; off <<= 1) v += __shfl_xor(v, off);
        vals[i] = v;
    }
    int lane = tid & 63, wave = tid >> 6;
    if (lane == 0) {
        #pragma unroll
        for (int i = 0; i < 65; i++) part[wave][i] = vals[i];
    }
    __syncthreads();
    if (tid < 65) {
        float s = part[0][tid] + part[1][tid] + part[2][tid] + part[3][tid];
        atomicAdd(&dst[b * 65 + tid], s);
    }
}

// GEMM: out[b][n][o] = sum_c W[o][c] * X[b][n][c] + bias[o]   (point-major)
// MODE 1: leaky 0.2 -> bf16.  MODE 2: raw bf16 + group stats atomics.
// MODE 3: v + GN(sbuf) -> leaky 0.01 -> f32 out [b][o][n] (channel-planar).
template<int CIN, int COUT, int GROUP_CH, int MODE>
__launch_bounds__(256)
__global__ void gemm_conv(const short* __restrict__ wA,   // [COUT][CIN] bf16
                          const short* __restrict__ xB,   // [b][N][CIN] bf16
                          const float* __restrict__ bias,
                          short* __restrict__ outb,
                          float* __restrict__ outf,
                          float* __restrict__ stats,
                          const short* __restrict__ sbuf, // [b][N][512] bf16
                          const float* __restrict__ st_sc,
                          const float* __restrict__ gw,
                          const float* __restrict__ gb,
                          float sc_cnt)
{
    __shared__ short Abuf[128 * 40];
    __shared__ short Bbuf[128 * 40];
    __shared__ float sstat[32];
    __shared__ float smean[4], sinv[4];

    const int tid  = threadIdx.x;
    const int n0   = blockIdx.x * 128;
    const int mo   = blockIdx.y * 128;
    const int b    = blockIdx.z;
    const int lane = tid & 63;
    const int wave = tid >> 6;
    const int wm   = (wave >> 1) * 64;
    const int wn   = (wave & 1) * 64;
    const int l15  = lane & 15;
    const int quad = lane >> 4;

    if constexpr (MODE == 2) { if (tid < 32) sstat[tid] = 0.f; }
    if constexpr (MODE == 3) {
        if (tid < 4) {
            int g = (mo >> 5) + tid;
            float s0 = st_sc[(b * 16 + g) * 2 + 0];
            float s1 = st_sc[(b * 16 + g) * 2 + 1];
            float mean = s0 / sc_cnt;
            float var  = s1 / sc_cnt - mean * mean;
            smean[tid] = mean;
            sinv[tid]  = rsqrtf(var + EPSc);
        }
    }

    floatx4 acc[4][4];
    #pragma unroll
    for (int mi = 0; mi < 4; mi++)
        #pragma unroll
        for (int ni = 0; ni < 4; ni++)
            acc[mi][ni] = (floatx4){0.f, 0.f, 0.f, 0.f};

    const short* wAr = wA + (size_t)mo * CIN;
    const short* xBr = xB + (size_t)b * Nc * CIN + (size_t)n0 * CIN;

    for (int c0 = 0; c0 < CIN; c0 += 32) {
        __syncthreads();
        #pragma unroll
        for (int s = 0; s < 2; s++) {
            int e = tid + s * 256;
            int r = e >> 2, q = e & 3;
            *(short8*)&Abuf[r * 40 + q * 8] =
                *(const short8*)(wAr + (size_t)r * CIN + c0 + q * 8);
            *(short8*)&Bbuf[r * 40 + q * 8] =
                *(const short8*)(xBr + (size_t)r * CIN + c0 + q * 8);
        }
        __syncthreads();

        short8 af[4], bfr[4];
        #pragma unroll
        for (int mi = 0; mi < 4; mi++)
            af[mi] = *(short8*)&Abuf[(wm + mi * 16 + l15) * 40 + quad * 8];
        #pragma unroll
        for (int ni = 0; ni < 4; ni++)
            bfr[ni] = *(short8*)&Bbuf[(wn + ni * 16 + l15) * 40 + quad * 8];
        #pragma unroll
        for (int mi = 0; mi < 4; mi++)
            #pragma unroll
            for (int ni = 0; ni < 4; ni++)
                acc[mi][ni] = __builtin_amdgcn_mfma_f32_16x16x32_bf16(
                    af[mi], bfr[ni], acc[mi][ni], 0, 0, 0);
    }

    // D row(o) = mo+wm+mi*16+quad*4+r, col(n) = n0+wn+ni*16+l15
    #pragma unroll
    for (int mi = 0; mi < 4; mi++) {
        int rowl = wm + mi * 16 + quad * 4;
        float b4[4], gw4[4], gb4[4];
        #pragma unroll
        for (int r = 0; r < 4; r++) {
            b4[r] = bias[mo + rowl + r];
            if constexpr (MODE == 3) {
                gw4[r] = gw[mo + rowl + r];
                gb4[r] = gb[mo + rowl + r];
            }
        }
        float gs = 0.f, gq = 0.f;
        #pragma unroll
        for (int ni = 0; ni < 4; ni++) {
            int col = n0 + wn + ni * 16 + l15;
            if constexpr (MODE == 3) {
                short4v s4 = *(const short4v*)&sbuf[((size_t)(b * Nc + col)) * 512 + mo + rowl];
                int gl = rowl >> 5;
                #pragma unroll
                for (int r = 0; r < 4; r++) {
                    float v = acc[mi][ni][r] + b4[r];
                    float s = bf2f(s4[r]);
                    float sn = (s - smean[gl]) * sinv[gl] * gw4[r] + gb4[r];
                    float o = v + sn;
                    o = o > 0.f ? o : 0.01f * o;
                    outf[((size_t)b * COUT + mo + rowl + r) * Nc + col] = o;
                }
            } else {
                short4v sv;
                #pragma unroll
                for (int r = 0; r < 4; r++) {
                    float v = acc[mi][ni][r] + b4[r];
                    if constexpr (MODE == 1) v = v > 0.f ? v : 0.2f * v;
                    if constexpr (MODE == 2) { gs += v; gq += v * v; }
                    sv[r] = f2bf(v);
                }
                *(short4v*)&outb[((size_t)(b * Nc + col)) * COUT + mo + rowl] = sv;
            }
        }
        if constexpr (MODE == 2) {
            #pragma unroll
            for (int off = 1; off < 16; off <<= 1) {
                gs += __shfl_xor(gs, off);
                gq += __shfl_xor(gq, off);
            }
            if (l15 == 0) {
                int gl = rowl / GROUP_CH;
                atomicAdd(&sstat[gl * 2 + 0], gs);
                atomicAdd(&sstat[gl * 2 + 1], gq);
            }
        }
    }
    if constexpr (MODE == 2) {
        __syncthreads();
        constexpr int NG = 128 / GROUP_CH;
        if (tid < 2 * NG) {
            int g0 = mo / GROUP_CH;
            atomicAdd(&stats[b * 32 + (g0 + (tid >> 1)) * 2 + (tid & 1)], sstat[tid]);
        }
    }
}

// LSE fused: per 16-point tile.
//  - per-group GN stats from closed form (S/Q + f32 weights), per-block.
//  - geo conv via MFMA (K padded to 32), GN+relu+mean_k -> m[n][0:128]
//  - neighbor gather-mean of point-major xprev -> m[n][128:256]
__launch_bounds__(256)
__global__ void lse_m_kernel(const float* __restrict__ coords,
                             const int* __restrict__ knn_idx,
                             const float* __restrict__ knn_dist,
                             const short* __restrict__ xprev,   // [b][N][128] bf16
                             const short* __restrict__ wpad,    // [128][32] bf16
                             const float* __restrict__ wf,      // [128][10] f32
                             const float* __restrict__ bias,    // [128]
                             const float* __restrict__ gw,
                             const float* __restrict__ gb,
                             const float* __restrict__ geoS,    // [B][65]
                             short* __restrict__ m)             // [b][N][256] bf16
{
    __shared__ short Abuf[128 * 40];
    __shared__ short Bbuf[256 * 40];
    __shared__ int   jl[256];
    __shared__ float osum[128], osq[128];
    __shared__ float smean[16], sinv[16];

    const int tid = threadIdx.x;
    const int b   = blockIdx.x >> 10;          // Nc/16 = 1024
    const int n0  = (blockIdx.x & 1023) * 16;
    const float NK = (float)(Nc * Kc);

    // zero Bbuf (pad cols must be 0)
    {
        int* bz = (int*)Bbuf;
        #pragma unroll
        for (int i = 0; i < 20; i++) bz[tid + i * 256] = 0;
    }
    // stage A (padded weights)
    #pragma unroll
    for (int s = 0; s < 2; s++) {
        int e = tid + s * 256;
        int o = e >> 2, q = e & 3;
        *(short8*)&Abuf[o * 40 + q * 8] = *(const short8*)(wpad + o * 32 + q * 8);
    }
    // closed-form per-channel sums
    if (tid < 128) {
        const float* S = geoS + b * 65;
        float w[10];
        #pragma unroll
        for (int c = 0; c < 10; c++) w[c] = wf[tid * 10 + c];
        float wS = 0.f;
        #pragma unroll
        for (int c = 0; c < 10; c++) wS += w[c] * S[c];
        float q = 0.f;
        {
            int idx = 10;
            #pragma unroll
            for (int c = 0; c < 10; c++)
                #pragma unroll
                for (int c2 = c; c2 < 10; c2++) {
                    float t = w[c] * w[c2] * S[idx++];
                    q += (c == c2) ? t : 2.f * t;
                }
        }
        float bo = bias[tid];
        osum[tid] = NK * bo + wS;
        osq[tid]  = NK * bo * bo + 2.f * bo * wS + q;
    }
    __syncthreads();   // Bbuf zero visible before geo writes? (geo writes below overwrite c<10 only)

    // geo features for the 16x16 (pt,k) tile -> Bbuf[col=k*16+pt][c]
    {
        int pt = tid & 15, k = tid >> 4;
        int n  = n0 + pt;
        const float* cb = coords + (size_t)b * Nc * 3;
        float cx = cb[n*3+0], cy = cb[n*3+1], cz = cb[n*3+2];
        int   j  = knn_idx[((size_t)b * Nc + n) * Kc + k];
        float nx = cb[j*3+0], ny = cb[j*3+1], nz = cb[j*3+2];
        float d  = knn_dist[((size_t)b * Nc + n) * Kc + k];
        float g[10] = {cx,cy,cz,nx,ny,nz,cx-nx,cy-ny,cz-nz,d};
        int col = k * 16 + pt;
        #pragma unroll
        for (int c = 0; c < 10; c++) Bbuf[col * 40 + c] = f2bf(g[c]);
        jl[col] = j;
    }
    __syncthreads();
    if (tid < 16) {
        float s = 0.f, q = 0.f;
        #pragma unroll
        for (int i = 0; i < 8; i++) { s += osum[tid * 8 + i]; q += osq[tid * 8 + i]; }
        float cnt  = 8.f * NK;
        float mean = s / cnt;
        float var  = q / cnt - mean * mean;
        smean[tid] = mean;
        sinv[tid]  = rsqrtf(var + EPSc);
    }
    __syncthreads();

    const int lane = tid & 63, wave = tid >> 6;
    const int l15 = lane & 15, quad = lane >> 4;
    // B fragments: tile ni <-> neighbor k, lane col <-> pt
    short8 bfr[16];
    #pragma unroll
    for (int ni = 0; ni < 16; ni++)
        bfr[ni] = *(short8*)&Bbuf[(ni * 16 + l15) * 40 + quad * 8];
    #pragma unroll
    for (int mt2 = 0; mt2 < 2; mt2++) {
        int mt = wave * 2 + mt2;
        short8 af = *(short8*)&Abuf[(mt * 16 + l15) * 40 + quad * 8];
        floatx4 acc[16];
        #pragma unroll
        for (int ni = 0; ni < 16; ni++) {
            acc[ni] = (floatx4){0.f, 0.f, 0.f, 0.f};
            acc[ni] = __builtin_amdgcn_mfma_f32_16x16x32_bf16(af, bfr[ni], acc[ni], 0, 0, 0);
        }
        short4v sv;
        #pragma unroll
        for (int r = 0; r < 4; r++) {
            int o = mt * 16 + quad * 4 + r;
            int g = o >> 3;
            float mu = smean[g], iv = sinv[g];
            float bo = bias[o], gwo = gw[o], gbo = gb[o];
            float s = 0.f;
            #pragma unroll
            for (int ni = 0; ni < 16; ni++) {
                float v = (acc[ni][r] + bo - mu) * iv * gwo + gbo;
                s += v > 0.f ? v : 0.f;
            }
            sv[r] = f2bf(s * (1.f / 16.f));
        }
        *(short4v*)&m[((size_t)(b * Nc + n0 + l15)) * 256 + mt * 16 + quad * 4] = sv;
    }

    // neighbor gather-mean: thread (cs, tp), 16 x b128 loads
    {
        int tp = tid & 15, cs = tid >> 4;
        float acc8[8];
        #pragma unroll
        for (int i = 0; i < 8; i++) acc8[i] = 0.f;
        #pragma unroll
        for (int k = 0; k < 16; k++) {
            int j = jl[k * 16 + tp];
            short8 v = *(const short8*)&xprev[((size_t)(b * Nc + j)) * 128 + cs * 8];
            #pragma unroll
            for (int i = 0; i < 8; i++) acc8[i] += bf2f(v[i]);
        }
        short8 sv;
        #pragma unroll
        for (int i = 0; i < 8; i++) sv[i] = f2bf(acc8[i] * (1.f / 16.f));
        *(short8*)&m[((size_t)(b * Nc + n0 + tp)) * 256 + 128 + cs * 8] = sv;
    }
}

// Elementwise GN + relu on bf16 point-major, in place, short8-vectorized.
template<int C, int GROUP_CH>
__launch_bounds__(256)
__global__ void gn_relu_kernel(short* __restrict__ z,
                               const float* __restrict__ stats,
                               const float* __restrict__ gw,
                               const float* __restrict__ gb,
                               float cnt)
{
    size_t base = ((size_t)blockIdx.x * 256 + threadIdx.x) * 8;
    int c0 = (int)(base % C);
    int b  = (int)(base / ((size_t)Nc * C));
    int g  = c0 / GROUP_CH;
    float s0 = stats[(b * 16 + g) * 2 + 0];
    float s1 = stats[(b * 16 + g) * 2 + 1];
    float mean = s0 / cnt;
    float var  = s1 / cnt - mean * mean;
    float inv  = rsqrtf(var + EPSc);
    short8 v = *(short8*)&z[base];
    short8 o;
    #pragma unroll
    for (int i = 0; i < 8; i++) {
        float x = (bf2f(v[i]) - mean) * inv * gw[c0 + i] + gb[c0 + i];
        o[i] = f2bf(x > 0.f ? x : 0.f);
    }
    *(short8*)&z[base] = o;
}

extern "C" void kernel_launch(void* const* d_in, const int* in_sizes, int n_in,
                              void* d_out, int out_size, void* d_ws, size_t ws_size,
                              hipStream_t stream)
{
    const float* coords   = (const float*)d_in[0];
    const float* features = (const float*)d_in[1];
    const float* knn_dist = (const float*)d_in[2];
    const int*   knn_idx  = (const int*)  d_in[3];
    const float* w1       = (const float*)d_in[4];
    const float* b1       = (const float*)d_in[5];
    const float* lse1_w   = (const float*)d_in[6];
    const float* lse1_b   = (const float*)d_in[7];
    const float* lse1_gw  = (const float*)d_in[8];
    const float* lse1_gb  = (const float*)d_in[9];
    const float* pool1_w  = (const float*)d_in[10];
    const float* pool1_b  = (const float*)d_in[11];
    const float* pool1_gw = (const float*)d_in[12];
    const float* pool1_gb = (const float*)d_in[13];
    const float* lse2_w   = (const float*)d_in[14];
    const float* lse2_b   = (const float*)d_in[15];
    const float* lse2_gw  = (const float*)d_in[16];
    const float* lse2_gb  = (const float*)d_in[17];
    const float* pool2_w  = (const float*)d_in[18];
    const float* pool2_b  = (const float*)d_in[19];
    const float* pool2_gw = (const float*)d_in[20];
    const float* pool2_gb = (const float*)d_in[21];
    const float* mlp2_w   = (const float*)d_in[22];
    const float* mlp2_b   = (const float*)d_in[23];
    const float* sc_w     = (const float*)d_in[24];
    const float* sc_b     = (const float*)d_in[25];
    const float* sc_gw    = (const float*)d_in[26];
    const float* sc_gb    = (const float*)d_in[27];
    (void)in_sizes; (void)n_in; (void)out_size; (void)ws_size;

    float* ST = (float*)d_ws;           // 1024 floats
    float* ST_SC  = ST + 0;
    float* ST_P1  = ST + 64;
    float* ST_P2  = ST + 128;
    float* ST_GEO = ST + 256;           // B x 65
    short* W16 = (short*)(ST + 1024);
    short* W1b  = W16 + OW_W1;
    short* P1Wb = W16 + OW_P1W;
    short* P2Wb = W16 + OW_P2W;
    short* M2Wb = W16 + OW_M2W;
    short* SCWb = W16 + OW_SCW;
    short* L1Wb = W16 + OW_L1W;
    short* L2Wb = W16 + OW_L2W;
    short* FB   = W16 + OW_FB;
    short* X1B  = W16 + OW_X1;
    short* MB   = W16 + OW_M;
    short* Z1   = W16 + OW_Z1;
    short* Z2   = W16 + OW_Z2;
    short* SB   = W16 + OW_S;
    float* out  = (float*)d_out;

    zero_kernel<<<4, 256, 0, stream>>>(ST, 1024);

    cvt_kernel<<<64, 256, 0, stream>>>(w1, W1b, 128*128);
    cvt_kernel<<<128, 256, 0, stream>>>(pool1_w, P1Wb, 128*256);
    cvt_kernel<<<256, 256, 0, stream>>>(pool2_w, P2Wb, 256*256);
    cvt_kernel<<<512, 256, 0, stream>>>(mlp2_w, M2Wb, 512*256);
    cvt_kernel<<<256, 256, 0, stream>>>(sc_w, SCWb, 512*128);
    cvt_pad_kernel<<<16, 256, 0, stream>>>(lse1_w, L1Wb);
    cvt_pad_kernel<<<16, 256, 0, stream>>>(lse2_w, L2Wb);
    feat_t_kernel<<<Bc * Nc / 64, 256, 0, stream>>>(features, FB);
    geo_reduce_kernel<<<Bc * Nc * Kc / 256, 256, 0, stream>>>(
        coords, knn_idx, knn_dist, ST_GEO);

    // sc: 128 -> 512, raw bf16 S + stats (group=32ch)
    gemm_conv<128,512,32,2><<<dim3(Nc/128, 4, Bc), 256, 0, stream>>>(
        SCWb, FB, sc_b, SB, nullptr, ST_SC, nullptr, nullptr, nullptr, nullptr, 0.f);
    // mlp1: 128 -> 128, leaky 0.2
    gemm_conv<128,128,8,1><<<dim3(Nc/128, 1, Bc), 256, 0, stream>>>(
        W1b, FB, b1, X1B, nullptr, nullptr, nullptr, nullptr, nullptr, nullptr, 0.f);
    // lse1
    lse_m_kernel<<<Bc * Nc / 16, 256, 0, stream>>>(
        coords, knn_idx, knn_dist, X1B, L1Wb, lse1_w, lse1_b, lse1_gw, lse1_gb,
        ST_GEO, MB);
    // pool1: 256 -> 128 + stats (group=8ch)
    gemm_conv<256,128,8,2><<<dim3(Nc/128, 1, Bc), 256, 0, stream>>>(
        P1Wb, MB, pool1_b, Z1, nullptr, ST_P1, nullptr, nullptr, nullptr, nullptr, 0.f);
    gn_relu_kernel<128,8><<<(Bc*128*Nc/8)/256, 256, 0, stream>>>(
        Z1, ST_P1, pool1_gw, pool1_gb, (float)(8 * Nc));
    // lse2
    lse_m_kernel<<<Bc * Nc / 16, 256, 0, stream>>>(
        coords, knn_idx, knn_dist, Z1, L2Wb, lse2_w, lse2_b, lse2_gw, lse2_gb,
        ST_GEO, MB);
    // pool2: 256 -> 256 + stats (group=16ch)
    gemm_conv<256,256,16,2><<<dim3(Nc/128, 2, Bc), 256, 0, stream>>>(
        P2Wb, MB, pool2_b, Z2, nullptr, ST_P2, nullptr, nullptr, nullptr, nullptr, 0.f);
    gn_relu_kernel<256,16><<<(Bc*256*Nc/8)/256, 256, 0, stream>>>(
        Z2, ST_P2, pool2_gw, pool2_gb, (float)(16 * Nc));
    // final: mlp2(x3) + GN(S) -> leaky 0.01 -> f32 out (channel-planar)
    gemm_conv<256,512,32,3><<<dim3(Nc/128, 4, Bc), 256, 0, stream>>>(
        M2Wb, Z2, mlp2_b, nullptr, out, nullptr, SB, ST_SC, sc_gw, sc_gb,
        (float)(32 * Nc));
}

// Round 4
// 350.113 us; speedup vs baseline: 6.7112x; 1.1104x over previous
//
#include <hip/hip_runtime.h>

// LocalFeatureAggregation — bf16-MFMA pipeline, point-major activations.
// B=2, N=16384, K=16, D_IN=128, D_OUT=256, GROUPS=16.
//
// Round-4 changes:
//  - geo_reduce: grid-stride register accumulation (4 items/thread) before the
//    65x6 shfl butterfly (was 1 item/butterfly -> latency-bound, 67.8 us).
//  - pool1 GN+relu folded into lse2's gather (per-channel scale/shift).
//  - pool2 GN+relu folded into the final GEMM's B-staging.
//  - all weight conversions + stat zeroing merged into one prep_kernel.

constexpr int Bc = 2;
constexpr int Nc = 16384;
constexpr int Kc = 16;
constexpr float EPSc = 1e-6f;

typedef __attribute__((ext_vector_type(8))) short short8;
typedef __attribute__((ext_vector_type(4))) short short4v;
typedef __attribute__((ext_vector_type(4))) float floatx4;

__device__ inline short f2bf(float x) {
    union { float f; unsigned u; } v; v.f = x;
    unsigned r = v.u + 0x7fffu + ((v.u >> 16) & 1u);
    return (short)(r >> 16);
}
__device__ inline float bf2f(short s) {
    union { unsigned u; float f; } v;
    v.u = ((unsigned)(unsigned short)s) << 16;
    return v.f;
}

// ---- workspace layout ----
// f32 ST[1024]: ST_SC=0, ST_P1=64, ST_P2=128, ST_GEO=256 (B x 65)
// then bf16 (short) region, offsets in shorts:
constexpr size_t OW_W1  = 0;                        // 128*128
constexpr size_t OW_P1W = OW_W1  + 128*128;         // 128*256
constexpr size_t OW_P2W = OW_P1W + 128*256;         // 256*256
constexpr size_t OW_M2W = OW_P2W + 256*256;         // 512*256
constexpr size_t OW_SCW = OW_M2W + 512*256;         // 512*128
constexpr size_t OW_L1W = OW_SCW + 512*128;         // 128*32 (K padded)
constexpr size_t OW_L2W = OW_L1W + 128*32;          // 128*32
constexpr size_t OW_FB  = OW_L2W + 128*32;          // B*N*128
constexpr size_t OW_X1  = OW_FB  + (size_t)Bc*Nc*128;
constexpr size_t OW_M   = OW_X1  + (size_t)Bc*Nc*128;
constexpr size_t OW_Z1  = OW_M   + (size_t)Bc*Nc*256;
constexpr size_t OW_Z2  = OW_Z1  + (size_t)Bc*Nc*128;
constexpr size_t OW_S   = OW_Z2  + (size_t)Bc*Nc*256;

// prep_kernel segment bounds (elements)
constexpr int CV0 = 128*128;            // w1
constexpr int CV1 = CV0 + 128*256;      // pool1_w
constexpr int CV2 = CV1 + 256*256;      // pool2_w
constexpr int CV3 = CV2 + 512*256;      // mlp2_w
constexpr int CV4 = CV3 + 512*128;      // sc_w
constexpr int CV5 = CV4 + 128*32;       // lse1_w padded
constexpr int CV6 = CV5 + 128*32;       // lse2_w padded
constexpr int CVTOT = CV6 + 1024;       // + zero ST

__global__ void prep_kernel(const float* __restrict__ w1,
                            const float* __restrict__ p1w,
                            const float* __restrict__ p2w,
                            const float* __restrict__ m2w,
                            const float* __restrict__ scw,
                            const float* __restrict__ l1w,
                            const float* __restrict__ l2w,
                            short* __restrict__ W16,
                            float* __restrict__ ST)
{
    int i = blockIdx.x * 256 + threadIdx.x;
    if (i < CV0) { W16[OW_W1  + i] = f2bf(w1[i]); return; }
    if (i < CV1) { int k = i - CV0; W16[OW_P1W + k] = f2bf(p1w[k]); return; }
    if (i < CV2) { int k = i - CV1; W16[OW_P2W + k] = f2bf(p2w[k]); return; }
    if (i < CV3) { int k = i - CV2; W16[OW_M2W + k] = f2bf(m2w[k]); return; }
    if (i < CV4) { int k = i - CV3; W16[OW_SCW + k] = f2bf(scw[k]); return; }
    if (i < CV5) { int k = i - CV4; int o = k >> 5, c = k & 31;
                   W16[OW_L1W + k] = (c < 10) ? f2bf(l1w[o*10+c]) : (short)0; return; }
    if (i < CV6) { int k = i - CV5; int o = k >> 5, c = k & 31;
                   W16[OW_L2W + k] = (c < 10) ? f2bf(l2w[o*10+c]) : (short)0; return; }
    { int k = i - CV6; if (k < 1024) ST[k] = 0.f; }
}

// features f32 [b][128][N] -> FB bf16 [b][N][128]
__global__ void feat_t_kernel(const float* __restrict__ in, short* __restrict__ out) {
    int tid  = threadIdx.x;
    int lane = tid & 63, wave = tid >> 6;
    int bb = blockIdx.x / (Nc / 64);
    int n  = (blockIdx.x % (Nc / 64)) * 64 + lane;
    #pragma unroll
    for (int cc = 0; cc < 4; cc++) {
        int c0 = (wave + cc * 4) * 8;
        short8 sv;
        #pragma unroll
        for (int i = 0; i < 8; i++)
            sv[i] = f2bf(in[((size_t)bb * 128 + c0 + i) * Nc + n]);
        *(short8*)&out[((size_t)(bb * Nc + n)) * 128 + c0] = sv;
    }
}

// Reduce S (10) and Q upper-tri (55) of geo over all (n,k), per batch.
// Grid-stride: 4 items accumulated in registers, then one butterfly/thread.
__launch_bounds__(256)
__global__ void geo_reduce_kernel(const float* __restrict__ coords,
                                  const int* __restrict__ knn_idx,
                                  const float* __restrict__ knn_dist,
                                  float* __restrict__ dst)   // [B][65]
{
    __shared__ float part[4][65];
    const int tid  = threadIdx.x;
    const int b    = blockIdx.y;
    const int base = blockIdx.x * 256 + tid;          // gridDim.x = 256
    const float* cb  = coords   + (size_t)b * Nc * 3;
    const int*   ib  = knn_idx  + (size_t)b * Nc * Kc;
    const float* db  = knn_dist + (size_t)b * Nc * Kc;

    float acc[65];
    #pragma unroll
    for (int i = 0; i < 65; i++) acc[i] = 0.f;

    #pragma unroll
    for (int it = 0; it < 4; it++) {
        int r = base + it * 65536;                    // covers Nc*Kc = 262144
        int n = r >> 4;
        float cx = cb[n*3+0], cy = cb[n*3+1], cz = cb[n*3+2];
        int   j  = ib[r];
        float nx = cb[j*3+0], ny = cb[j*3+1], nz = cb[j*3+2];
        float d  = db[r];
        float g[10] = {cx,cy,cz,nx,ny,nz,cx-nx,cy-ny,cz-nz,d};
        #pragma unroll
        for (int c = 0; c < 10; c++) acc[c] += g[c];
        int idx = 10;
        #pragma unroll
        for (int c = 0; c < 10; c++)
            #pragma unroll
            for (int c2 = c; c2 < 10; c2++) acc[idx++] += g[c] * g[c2];
    }
    #pragma unroll
    for (int i = 0; i < 65; i++) {
        float v = acc[i];
        #pragma unroll
        for (int off = 1; off < 64; off <<= 1) v += __shfl_xor(v, off);
        acc[i] = v;
    }
    int lane = tid & 63, wave = tid >> 6;
    if (lane == 0) {
        #pragma unroll
        for (int i = 0; i < 65; i++) part[wave][i] = acc[i];
    }
    __syncthreads();
    if (tid < 65) {
        float s = part[0][tid] + part[1][tid] + part[2][tid] + part[3][tid];
        atomicAdd(&dst[b * 65 + tid], s);
    }
}

// GEMM: out[b][n][o] = sum_c W[o][c] * X[b][n][c] + bias[o]   (point-major)
// MODE 1: leaky 0.2 -> bf16.  MODE 2: raw bf16 + group stats atomics.
// MODE 3: final — B input normalized during staging (pool2 GN+relu, 16ch
//         groups), epilogue v + GN(sbuf) -> leaky 0.01 -> f32 [b][o][n].
template<int CIN, int COUT, int GROUP_CH, int MODE>
__launch_bounds__(256)
__global__ void gemm_conv(const short* __restrict__ wA,   // [COUT][CIN] bf16
                          const short* __restrict__ xB,   // [b][N][CIN] bf16
                          const float* __restrict__ bias,
                          short* __restrict__ outb,
                          float* __restrict__ outf,
                          float* __restrict__ stats,
                          const short* __restrict__ sbuf, // [b][N][512] bf16
                          const float* __restrict__ st_sc,
                          const float* __restrict__ gw,
                          const float* __restrict__ gb,
                          float sc_cnt,
                          const float* __restrict__ bst,  // MODE 3: pool2 stats
                          const float* __restrict__ bgw,
                          const float* __restrict__ bgb,
                          float bcnt)
{
    __shared__ short Abuf[128 * 40];
    __shared__ short Bbuf[128 * 40];
    __shared__ float sstat[32];
    __shared__ float smean[4], sinv[4];
    __shared__ float bsc[256], bsh[256];

    const int tid  = threadIdx.x;
    const int n0   = blockIdx.x * 128;
    const int mo   = blockIdx.y * 128;
    const int b    = blockIdx.z;
    const int lane = tid & 63;
    const int wave = tid >> 6;
    const int wm   = (wave >> 1) * 64;
    const int wn   = (wave & 1) * 64;
    const int l15  = lane & 15;
    const int quad = lane >> 4;

    if constexpr (MODE == 2) { if (tid < 32) sstat[tid] = 0.f; }
    if constexpr (MODE == 3) {
        if (tid < 4) {
            int g = (mo >> 5) + tid;
            float s0 = st_sc[(b * 16 + g) * 2 + 0];
            float s1 = st_sc[(b * 16 + g) * 2 + 1];
            float mean = s0 / sc_cnt;
            float var  = s1 / sc_cnt - mean * mean;
            smean[tid] = mean;
            sinv[tid]  = rsqrtf(var + EPSc);
        }
        if (tid < CIN) {   // pool2 GN: 256 ch, 16 ch/group
            int g = tid >> 4;
            float s0 = bst[(b * 16 + g) * 2 + 0];
            float s1 = bst[(b * 16 + g) * 2 + 1];
            float mean = s0 / bcnt;
            float var  = s1 / bcnt - mean * mean;
            float inv  = rsqrtf(var + EPSc);
            float sc_  = inv * bgw[tid];
            bsc[tid] = sc_;
            bsh[tid] = bgb[tid] - mean * sc_;
        }
    }

    floatx4 acc[4][4];
    #pragma unroll
    for (int mi = 0; mi < 4; mi++)
        #pragma unroll
        for (int ni = 0; ni < 4; ni++)
            acc[mi][ni] = (floatx4){0.f, 0.f, 0.f, 0.f};

    const short* wAr = wA + (size_t)mo * CIN;
    const short* xBr = xB + (size_t)b * Nc * CIN + (size_t)n0 * CIN;

    for (int c0 = 0; c0 < CIN; c0 += 32) {
        __syncthreads();
        #pragma unroll
        for (int s = 0; s < 2; s++) {
            int e = tid + s * 256;
            int r = e >> 2, q = e & 3;
            *(short8*)&Abuf[r * 40 + q * 8] =
                *(const short8*)(wAr + (size_t)r * CIN + c0 + q * 8);
            short8 v = *(const short8*)(xBr + (size_t)r * CIN + c0 + q * 8);
            if constexpr (MODE == 3) {
                #pragma unroll
                for (int i = 0; i < 8; i++) {
                    int ch = c0 + q * 8 + i;
                    float t = bf2f(v[i]) * bsc[ch] + bsh[ch];
                    v[i] = f2bf(t > 0.f ? t : 0.f);
                }
            }
            *(short8*)&Bbuf[r * 40 + q * 8] = v;
        }
        __syncthreads();

        short8 af[4], bfr[4];
        #pragma unroll
        for (int mi = 0; mi < 4; mi++)
            af[mi] = *(short8*)&Abuf[(wm + mi * 16 + l15) * 40 + quad * 8];
        #pragma unroll
        for (int ni = 0; ni < 4; ni++)
            bfr[ni] = *(short8*)&Bbuf[(wn + ni * 16 + l15) * 40 + quad * 8];
        #pragma unroll
        for (int mi = 0; mi < 4; mi++)
            #pragma unroll
            for (int ni = 0; ni < 4; ni++)
                acc[mi][ni] = __builtin_amdgcn_mfma_f32_16x16x32_bf16(
                    af[mi], bfr[ni], acc[mi][ni], 0, 0, 0);
    }

    // D row(o) = mo+wm+mi*16+quad*4+r, col(n) = n0+wn+ni*16+l15
    #pragma unroll
    for (int mi = 0; mi < 4; mi++) {
        int rowl = wm + mi * 16 + quad * 4;
        float b4[4], gw4[4], gb4[4];
        #pragma unroll
        for (int r = 0; r < 4; r++) {
            b4[r] = bias[mo + rowl + r];
            if constexpr (MODE == 3) {
                gw4[r] = gw[mo + rowl + r];
                gb4[r] = gb[mo + rowl + r];
            }
        }
        float gs = 0.f, gq = 0.f;
        #pragma unroll
        for (int ni = 0; ni < 4; ni++) {
            int col = n0 + wn + ni * 16 + l15;
            if constexpr (MODE == 3) {
                short4v s4 = *(const short4v*)&sbuf[((size_t)(b * Nc + col)) * 512 + mo + rowl];
                int gl = rowl >> 5;
                #pragma unroll
                for (int r = 0; r < 4; r++) {
                    float v = acc[mi][ni][r] + b4[r];
                    float s = bf2f(s4[r]);
                    float sn = (s - smean[gl]) * sinv[gl] * gw4[r] + gb4[r];
                    float o = v + sn;
                    o = o > 0.f ? o : 0.01f * o;
                    outf[((size_t)b * COUT + mo + rowl + r) * Nc + col] = o;
                }
            } else {
                short4v sv;
                #pragma unroll
                for (int r = 0; r < 4; r++) {
                    float v = acc[mi][ni][r] + b4[r];
                    if constexpr (MODE == 1) v = v > 0.f ? v : 0.2f * v;
                    if constexpr (MODE == 2) { gs += v; gq += v * v; }
                    sv[r] = f2bf(v);
                }
                *(short4v*)&outb[((size_t)(b * Nc + col)) * COUT + mo + rowl] = sv;
            }
        }
        if constexpr (MODE == 2) {
            #pragma unroll
            for (int off = 1; off < 16; off <<= 1) {
                gs += __shfl_xor(gs, off);
                gq += __shfl_xor(gq, off);
            }
            if (l15 == 0) {
                int gl = rowl / GROUP_CH;
                atomicAdd(&sstat[gl * 2 + 0], gs);
                atomicAdd(&sstat[gl * 2 + 1], gq);
            }
        }
    }
    if constexpr (MODE == 2) {
        __syncthreads();
        constexpr int NG = 128 / GROUP_CH;
        if (tid < 2 * NG) {
            int g0 = mo / GROUP_CH;
            atomicAdd(&stats[b * 32 + (g0 + (tid >> 1)) * 2 + (tid & 1)], sstat[tid]);
        }
    }
}

// LSE fused: per 16-point tile.
//  - per-group GN stats from closed form (S/Q + f32 weights), per-block.
//  - geo conv via MFMA (K padded to 32), GN+relu+mean_k -> m[n][0:128]
//  - neighbor gather-mean of point-major xprev -> m[n][128:256];
//    optional folded GN+relu on xprev (xst != nullptr: pool1 stats, 8ch groups)
__launch_bounds__(256)
__global__ void lse_m_kernel(const float* __restrict__ coords,
                             const int* __restrict__ knn_idx,
                             const float* __restrict__ knn_dist,
                             const short* __restrict__ xprev,   // [b][N][128] bf16
                             const short* __restrict__ wpad,    // [128][32] bf16
                             const float* __restrict__ wf,      // [128][10] f32
                             const float* __restrict__ bias,    // [128]
                             const float* __restrict__ gw,
                             const float* __restrict__ gb,
                             const float* __restrict__ geoS,    // [B][65]
                             const float* __restrict__ xst,     // pool1 stats or null
                             const float* __restrict__ xgw,
                             const float* __restrict__ xgb,
                             float xcnt,
                             short* __restrict__ m)             // [b][N][256] bf16
{
    __shared__ short Abuf[128 * 40];
    __shared__ short Bbuf[256 * 40];
    __shared__ int   jl[256];
    __shared__ float osum[128], osq[128];
    __shared__ float smean[16], sinv[16];
    __shared__ float xscs[128], xshs[128];

    const int tid = threadIdx.x;
    const int b   = blockIdx.x >> 10;          // Nc/16 = 1024
    const int n0  = (blockIdx.x & 1023) * 16;
    const float NK = (float)(Nc * Kc);
    const bool norm = (xst != nullptr);

    // zero Bbuf (pad cols must be 0)
    {
        int* bz = (int*)Bbuf;
        #pragma unroll
        for (int i = 0; i < 20; i++) bz[tid + i * 256] = 0;
    }
    // stage A (padded weights)
    #pragma unroll
    for (int s = 0; s < 2; s++) {
        int e = tid + s * 256;
        int o = e >> 2, q = e & 3;
        *(short8*)&Abuf[o * 40 + q * 8] = *(const short8*)(wpad + o * 32 + q * 8);
    }
    // closed-form per-channel sums + xprev GN scale/shift
    if (tid < 128) {
        const float* S = geoS + b * 65;
        float w[10];
        #pragma unroll
        for (int c = 0; c < 10; c++) w[c] = wf[tid * 10 + c];
        float wS = 0.f;
        #pragma unroll
        for (int c = 0; c < 10; c++) wS += w[c] * S[c];
        float q = 0.f;
        {
            int idx = 10;
            #pragma unroll
            for (int c = 0; c < 10; c++)
                #pragma unroll
                for (int c2 = c; c2 < 10; c2++) {
                    float t = w[c] * w[c2] * S[idx++];
                    q += (c == c2) ? t : 2.f * t;
                }
        }
        float bo = bias[tid];
        osum[tid] = NK * bo + wS;
        osq[tid]  = NK * bo * bo + 2.f * bo * wS + q;
        if (norm) {   // pool1 GN: 128 ch, 8 ch/group
            int g = tid >> 3;
            float s0 = xst[(b * 16 + g) * 2 + 0];
            float s1 = xst[(b * 16 + g) * 2 + 1];
            float mean = s0 / xcnt;
            float var  = s1 / xcnt - mean * mean;
            float inv  = rsqrtf(var + EPSc);
            float sc_  = inv * xgw[tid];
            xscs[tid] = sc_;
            xshs[tid] = xgb[tid] - mean * sc_;
        }
    }
    __syncthreads();

    // geo features for the 16x16 (pt,k) tile -> Bbuf[col=k*16+pt][c]
    {
        int pt = tid & 15, k = tid >> 4;
        int n  = n0 + pt;
        const float* cb = coords + (size_t)b * Nc * 3;
        float cx = cb[n*3+0], cy = cb[n*3+1], cz = cb[n*3+2];
        int   j  = knn_idx[((size_t)b * Nc + n) * Kc + k];
        float nx = cb[j*3+0], ny = cb[j*3+1], nz = cb[j*3+2];
        float d  = knn_dist[((size_t)b * Nc + n) * Kc + k];
        float g[10] = {cx,cy,cz,nx,ny,nz,cx-nx,cy-ny,cz-nz,d};
        int col = k * 16 + pt;
        #pragma unroll
        for (int c = 0; c < 10; c++) Bbuf[col * 40 + c] = f2bf(g[c]);
        jl[col] = j;
    }
    __syncthreads();
    if (tid < 16) {
        float s = 0.f, q = 0.f;
        #pragma unroll
        for (int i = 0; i < 8; i++) { s += osum[tid * 8 + i]; q += osq[tid * 8 + i]; }
        float cnt  = 8.f * NK;
        float mean = s / cnt;
        float var  = q / cnt - mean * mean;
        smean[tid] = mean;
        sinv[tid]  = rsqrtf(var + EPSc);
    }
    __syncthreads();

    const int lane = tid & 63, wave = tid >> 6;
    const int l15 = lane & 15, quad = lane >> 4;
    // B fragments: tile ni <-> neighbor k, lane col <-> pt
    short8 bfr[16];
    #pragma unroll
    for (int ni = 0; ni < 16; ni++)
        bfr[ni] = *(short8*)&Bbuf[(ni * 16 + l15) * 40 + quad * 8];
    #pragma unroll
    for (int mt2 = 0; mt2 < 2; mt2++) {
        int mt = wave * 2 + mt2;
        short8 af = *(short8*)&Abuf[(mt * 16 + l15) * 40 + quad * 8];
        floatx4 acc[16];
        #pragma unroll
        for (int ni = 0; ni < 16; ni++) {
            acc[ni] = (floatx4){0.f, 0.f, 0.f, 0.f};
            acc[ni] = __builtin_amdgcn_mfma_f32_16x16x32_bf16(af, bfr[ni], acc[ni], 0, 0, 0);
        }
        short4v sv;
        #pragma unroll
        for (int r = 0; r < 4; r++) {
            int o = mt * 16 + quad * 4 + r;
            int g = o >> 3;
            float mu = smean[g], iv = sinv[g];
            float bo = bias[o], gwo = gw[o], gbo = gb[o];
            float s = 0.f;
            #pragma unroll
            for (int ni = 0; ni < 16; ni++) {
                float v = (acc[ni][r] + bo - mu) * iv * gwo + gbo;
                s += v > 0.f ? v : 0.f;
            }
            sv[r] = f2bf(s * (1.f / 16.f));
        }
        *(short4v*)&m[((size_t)(b * Nc + n0 + l15)) * 256 + mt * 16 + quad * 4] = sv;
    }

    // neighbor gather-mean: thread (cs, tp), 16 x b128 loads
    {
        int tp = tid & 15, cs = tid >> 4;
        float sc8[8], sh8[8];
        if (norm) {
            #pragma unroll
            for (int i = 0; i < 8; i++) { sc8[i] = xscs[cs*8+i]; sh8[i] = xshs[cs*8+i]; }
        }
        float acc8[8];
        #pragma unroll
        for (int i = 0; i < 8; i++) acc8[i] = 0.f;
        #pragma unroll
        for (int k = 0; k < 16; k++) {
            int j = jl[k * 16 + tp];
            short8 v = *(const short8*)&xprev[((size_t)(b * Nc + j)) * 128 + cs * 8];
            if (norm) {
                #pragma unroll
                for (int i = 0; i < 8; i++) {
                    float t = bf2f(v[i]) * sc8[i] + sh8[i];
                    acc8[i] += t > 0.f ? t : 0.f;
                }
            } else {
                #pragma unroll
                for (int i = 0; i < 8; i++) acc8[i] += bf2f(v[i]);
            }
        }
        short8 sv;
        #pragma unroll
        for (int i = 0; i < 8; i++) sv[i] = f2bf(acc8[i] * (1.f / 16.f));
        *(short8*)&m[((size_t)(b * Nc + n0 + tp)) * 256 + 128 + cs * 8] = sv;
    }
}

extern "C" void kernel_launch(void* const* d_in, const int* in_sizes, int n_in,
                              void* d_out, int out_size, void* d_ws, size_t ws_size,
                              hipStream_t stream)
{
    const float* coords   = (const float*)d_in[0];
    const float* features = (const float*)d_in[1];
    const float* knn_dist = (const float*)d_in[2];
    const int*   knn_idx  = (const int*)  d_in[3];
    const float* w1       = (const float*)d_in[4];
    const float* b1       = (const float*)d_in[5];
    const float* lse1_w   = (const float*)d_in[6];
    const float* lse1_b   = (const float*)d_in[7];
    const float* lse1_gw  = (const float*)d_in[8];
    const float* lse1_gb  = (const float*)d_in[9];
    const float* pool1_w  = (const float*)d_in[10];
    const float* pool1_b  = (const float*)d_in[11];
    const float* pool1_gw = (const float*)d_in[12];
    const float* pool1_gb = (const float*)d_in[13];
    const float* lse2_w   = (const float*)d_in[14];
    const float* lse2_b   = (const float*)d_in[15];
    const float* lse2_gw  = (const float*)d_in[16];
    const float* lse2_gb  = (const float*)d_in[17];
    const float* pool2_w  = (const float*)d_in[18];
    const float* pool2_b  = (const float*)d_in[19];
    const float* pool2_gw = (const float*)d_in[20];
    const float* pool2_gb = (const float*)d_in[21];
    const float* mlp2_w   = (const float*)d_in[22];
    const float* mlp2_b   = (const float*)d_in[23];
    const float* sc_w     = (const float*)d_in[24];
    const float* sc_b     = (const float*)d_in[25];
    const float* sc_gw    = (const float*)d_in[26];
    const float* sc_gb    = (const float*)d_in[27];
    (void)in_sizes; (void)n_in; (void)out_size; (void)ws_size;

    float* ST = (float*)d_ws;           // 1024 floats
    float* ST_SC  = ST + 0;
    float* ST_P1  = ST + 64;
    float* ST_P2  = ST + 128;
    float* ST_GEO = ST + 256;           // B x 65
    short* W16 = (short*)(ST + 1024);
    short* W1b  = W16 + OW_W1;
    short* P1Wb = W16 + OW_P1W;
    short* P2Wb = W16 + OW_P2W;
    short* M2Wb = W16 + OW_M2W;
    short* SCWb = W16 + OW_SCW;
    short* L1Wb = W16 + OW_L1W;
    short* L2Wb = W16 + OW_L2W;
    short* FB   = W16 + OW_FB;
    short* X1B  = W16 + OW_X1;
    short* MB   = W16 + OW_M;
    short* Z1   = W16 + OW_Z1;
    short* Z2   = W16 + OW_Z2;
    short* SB   = W16 + OW_S;
    float* out  = (float*)d_out;

    prep_kernel<<<(CVTOT + 255) / 256, 256, 0, stream>>>(
        w1, pool1_w, pool2_w, mlp2_w, sc_w, lse1_w, lse2_w, W16, ST);
    feat_t_kernel<<<Bc * Nc / 64, 256, 0, stream>>>(features, FB);
    geo_reduce_kernel<<<dim3(256, Bc), 256, 0, stream>>>(
        coords, knn_idx, knn_dist, ST_GEO);

    // sc: 128 -> 512, raw bf16 S + stats (group=32ch)
    gemm_conv<128,512,32,2><<<dim3(Nc/128, 4, Bc), 256, 0, stream>>>(
        SCWb, FB, sc_b, SB, nullptr, ST_SC, nullptr, nullptr, nullptr, nullptr, 0.f,
        nullptr, nullptr, nullptr, 0.f);
    // mlp1: 128 -> 128, leaky 0.2
    gemm_conv<128,128,8,1><<<dim3(Nc/128, 1, Bc), 256, 0, stream>>>(
        W1b, FB, b1, X1B, nullptr, nullptr, nullptr, nullptr, nullptr, nullptr, 0.f,
        nullptr, nullptr, nullptr, 0.f);
    // lse1 (xprev = X1B, no folded GN)
    lse_m_kernel<<<Bc * Nc / 16, 256, 0, stream>>>(
        coords, knn_idx, knn_dist, X1B, L1Wb, lse1_w, lse1_b, lse1_gw, lse1_gb,
        ST_GEO, nullptr, nullptr, nullptr, 0.f, MB);
    // pool1: 256 -> 128 + stats (group=8ch), raw Z1
    gemm_conv<256,128,8,2><<<dim3(Nc/128, 1, Bc), 256, 0, stream>>>(
        P1Wb, MB, pool1_b, Z1, nullptr, ST_P1, nullptr, nullptr, nullptr, nullptr, 0.f,
        nullptr, nullptr, nullptr, 0.f);
    // lse2 (xprev = raw Z1, pool1 GN+relu folded into gather)
    lse_m_kernel<<<Bc * Nc / 16, 256, 0, stream>>>(
        coords, knn_idx, knn_dist, Z1, L2Wb, lse2_w, lse2_b, lse2_gw, lse2_gb,
        ST_GEO, ST_P1, pool1_gw, pool1_gb, (float)(8 * Nc), MB);
    // pool2: 256 -> 256 + stats (group=16ch), raw Z2
    gemm_conv<256,256,16,2><<<dim3(Nc/128, 2, Bc), 256, 0, stream>>>(
        P2Wb, MB, pool2_b, Z2, nullptr, ST_P2, nullptr, nullptr, nullptr, nullptr, 0.f,
        nullptr, nullptr, nullptr, 0.f);
    // final: mlp2(GN+relu(Z2) folded into staging) + GN(S) -> leaky 0.01 -> f32
    gemm_conv<256,512,32,3><<<dim3(Nc/128, 4, Bc), 256, 0, stream>>>(
        M2Wb, Z2, mlp2_b, nullptr, out, nullptr, SB, ST_SC, sc_gw, sc_gb,
        (float)(32 * Nc), ST_P2, pool2_gw, pool2_gb, (float)(16 * Nc));
}